// Round 22
// baseline (714.012 us; speedup 1.0000x reference)
//
#include <hip/hip_runtime.h>

#define N_NODES 50000
#define E_EDGES 200000
#define ET_EDGES (E_EDGES + N_NODES)
#define G_GRAPHS 2000
#define F_IN 64
#define HID 128
#define HEADS 4
#define DM 512
#define BN_EPS 1e-5f
#define NEG_SLOPE 0.2f
#define YBLK 391            // (N_NODES+127)/128
#define NCHUNK (YBLK / 8)   // 48 full 8-row chunks

typedef unsigned short ushort_t;
typedef float floatx4 __attribute__((ext_vector_type(4)));
typedef short short8 __attribute__((ext_vector_type(8)));

__device__ __forceinline__ float b2f(unsigned int u) {
    union { unsigned int i; float f; } v; v.i = u << 16; return v.f;
}
__device__ __forceinline__ ushort_t f2b(float f) {
    union { float f; unsigned int i; } v; v.f = f;
    unsigned int r = v.i + 0x7FFFu + ((v.i >> 16) & 1u);   // RNE
    return (ushort_t)(r >> 16);
}
__device__ __forceinline__ void unpack8(uint4 v, float* f) {
    f[0] = b2f(v.x & 0xffffu); f[1] = b2f(v.x >> 16);
    f[2] = b2f(v.y & 0xffffu); f[3] = b2f(v.y >> 16);
    f[4] = b2f(v.z & 0xffffu); f[5] = b2f(v.z >> 16);
    f[6] = b2f(v.w & 0xffffu); f[7] = b2f(v.w >> 16);
}

// ---------- combined prep: x->bf16 + 3x W[K,512]->Wt[512,K] bf16 ----------
#define XN (N_NODES * F_IN)
#define W0N (F_IN * DM)
#define W1N (DM * DM)
__global__ __launch_bounds__(256) void k_prep(const float* __restrict__ x,
                                              const float* __restrict__ w0,
                                              const float* __restrict__ w1,
                                              const float* __restrict__ w2,
                                              ushort_t* __restrict__ Xb,
                                              ushort_t* __restrict__ Wh0,
                                              ushort_t* __restrict__ Wh1,
                                              ushort_t* __restrict__ Wh2) {
    int t = blockIdx.x * 256 + threadIdx.x;
    if (t < XN) { Xb[t] = f2b(x[t]); return; }
    t -= XN;
    if (t < W0N) {
        int k = t >> 9, n = t & 511;
        Wh0[(size_t)n * F_IN + k] = f2b(w0[t]);
        return;
    }
    t -= W0N;
    if (t < W1N) {
        int k = t >> 9, n = t & 511;
        Wh1[(size_t)n * DM + k] = f2b(w1[t]);
        return;
    }
    t -= W1N;
    if (t < W1N) {
        int k = t >> 9, n = t & 511;
        Wh2[(size_t)n * DM + k] = f2b(w2[t]);
    }
}

// ---------- MFMA GEMM, software-pipelined: prefetch tile k+1 during MFMA ----------
// C[M,512](bf16) = f(A)[M,K] @ W, f(a)=max(a*scale+shift,0) if stat else a.
// XCD-grouped 1D grid; XOR-swizzled LDS.
__global__ __launch_bounds__(256) void k_mgemm(const ushort_t* __restrict__ A,
                                               const ushort_t* __restrict__ Bh,
                                               const float* __restrict__ stat,
                                               const float* __restrict__ gam,
                                               const float* __restrict__ bet,
                                               const float* __restrict__ a_s,
                                               const float* __restrict__ a_d,
                                               ushort_t* __restrict__ C,
                                               float* __restrict__ ssrc,
                                               float* __restrict__ sdst,
                                               int M, int K) {
    __shared__ __align__(16) ushort_t Ash[128 * 32];
    __shared__ __align__(16) ushort_t Bsh[128 * 32];
    __shared__ float sS[128], sD[128];
    __shared__ float sBs[512], sBt[512];
    // ---- XCD-grouping block index map ----
    int bid = blockIdx.x;
    int head, yb;
    if (bid < NCHUNK * 32) {
        int chunk = bid >> 5, pos = bid & 31;
        yb = chunk * 8 + (pos & 7);
        head = pos >> 3;
    } else {
        int rem = bid - NCHUNK * 32;
        head = rem & 3;
        yb = NCHUNK * 8 + (rem >> 2);
    }
    int m0 = yb * 128, n0 = head * 128;
    int tid = threadIdx.x;
    int lane = tid & 63, wave = tid >> 6;
    int wm = (wave >> 1) * 64, wn = (wave & 1) * 64;
    int r0 = tid >> 2, kv = tid & 3;
    floatx4 acc[4][4] = {};
    bool has_bn = (stat != nullptr);
    if (has_bn) {                     // fused bnfin: scale/shift from raw stats
        for (int f = tid; f < 512; f += 256) {
            float mu = stat[f] * (1.f / (float)N_NODES);
            float var = fmaxf(stat[512 + f] * (1.f / (float)N_NODES) - mu * mu, 0.f);
            float rs = rsqrtf(var + BN_EPS);
            float sc = gam[f] * rs;
            sBs[f] = sc;
            sBt[f] = bet[f] - mu * sc;
        }
    }
    if (tid < 128) { sS[tid] = 0.f; sD[tid] = 0.f; }
    int rA1 = m0 + r0;      if (rA1 >= M) rA1 = M - 1;
    int rA2 = m0 + r0 + 64; if (rA2 >= M) rA2 = M - 1;
    const ushort_t* pa1 = A + (size_t)rA1 * K + kv * 8;
    const ushort_t* pa2 = A + (size_t)rA2 * K + kv * 8;
    const ushort_t* pbh1 = Bh + (size_t)(n0 + r0) * K + kv * 8;
    const ushort_t* pbh2 = Bh + (size_t)(n0 + r0 + 64) * K + kv * 8;
    int rF = lane & 15, q = lane >> 4;
    int swz = ((q ^ (rF & 3) ^ ((rF >> 2) & 3))) * 8;        // read-side chunk pos
    int wswz = ((kv ^ (r0 & 3) ^ ((r0 >> 2) & 3))) * 8;      // write-side chunk pos
    // prefetch tile 0
    uint4 a1 = *(const uint4*)pa1;
    uint4 a2 = *(const uint4*)pa2;
    uint4 b1 = *(const uint4*)pbh1;
    uint4 b2 = *(const uint4*)pbh2;
    for (int k0 = 0; k0 < K; k0 += 32) {
        if (has_bn) {   // fused BN-apply + ReLU on the prefetched registers
            float v1[8], v2[8];
            unpack8(a1, v1); unpack8(a2, v2);
            const float* sp = sBs + k0 + kv * 8;
            const float* tp = sBt + k0 + kv * 8;
            unsigned* q1 = (unsigned*)&a1;
            unsigned* q2 = (unsigned*)&a2;
#pragma unroll
            for (int j = 0; j < 4; ++j) {
                float s0 = sp[2 * j], t0 = tp[2 * j];
                float s1 = sp[2 * j + 1], t1 = tp[2 * j + 1];
                unsigned lo1 = f2b(fmaxf(v1[2 * j] * s0 + t0, 0.f));
                unsigned hi1 = f2b(fmaxf(v1[2 * j + 1] * s1 + t1, 0.f));
                unsigned lo2 = f2b(fmaxf(v2[2 * j] * s0 + t0, 0.f));
                unsigned hi2 = f2b(fmaxf(v2[2 * j + 1] * s1 + t1, 0.f));
                q1[j] = lo1 | (hi1 << 16);
                q2[j] = lo2 | (hi2 << 16);
            }
        }
        __syncthreads();
        *(uint4*)&Ash[r0 * 32 + wswz] = a1;
        *(uint4*)&Ash[(r0 + 64) * 32 + wswz] = a2;
        *(uint4*)&Bsh[r0 * 32 + wswz] = b1;
        *(uint4*)&Bsh[(r0 + 64) * 32 + wswz] = b2;
        __syncthreads();
        if (k0 + 32 < K) {            // prefetch next tile; overlaps ds_read+MFMA
            a1 = *(const uint4*)(pa1 + k0 + 32);
            a2 = *(const uint4*)(pa2 + k0 + 32);
            b1 = *(const uint4*)(pbh1 + k0 + 32);
            b2 = *(const uint4*)(pbh2 + k0 + 32);
        }
        short8 af[4], bf[4];
#pragma unroll
        for (int i = 0; i < 4; ++i)
            af[i] = *(const short8*)&Ash[(wm + i * 16 + rF) * 32 + swz];
#pragma unroll
        for (int j = 0; j < 4; ++j)
            bf[j] = *(const short8*)&Bsh[(wn + j * 16 + rF) * 32 + swz];
#pragma unroll
        for (int i = 0; i < 4; ++i)
#pragma unroll
            for (int j = 0; j < 4; ++j)
                acc[i][j] = __builtin_amdgcn_mfma_f32_16x16x32_bf16(af[i], bf[j], acc[i][j], 0, 0, 0);
    }
    // C/D layout: col=lane&15, row=(lane>>4)*4+reg   [m89-verified]
    int cr = (lane >> 4) * 4, cc = lane & 15;
#pragma unroll
    for (int i = 0; i < 4; ++i) {
#pragma unroll
        for (int r = 0; r < 4; ++r) {
            int gr = m0 + wm + i * 16 + cr + r;
            if (gr < M) {
#pragma unroll
                for (int j = 0; j < 4; ++j)
                    C[(size_t)gr * DM + n0 + wn + j * 16 + cc] = f2b(acc[i][j][r]);
            }
        }
    }
    // ---- fused attention scores (f32 acc, pre-rounding): 128 cols == one head ----
    float asl_[4], adl_[4];
#pragma unroll
    for (int j = 0; j < 4; ++j) {
        int c = wn + j * 16 + cc;
        asl_[j] = a_s[head * HID + c];
        adl_[j] = a_d[head * HID + c];
    }
#pragma unroll
    for (int i = 0; i < 4; ++i) {
#pragma unroll
        for (int r = 0; r < 4; ++r) {
            float ps = 0.f, pd = 0.f;
#pragma unroll
            for (int j = 0; j < 4; ++j) {
                ps += acc[i][j][r] * asl_[j];
                pd += acc[i][j][r] * adl_[j];
            }
#pragma unroll
            for (int mk = 1; mk < 16; mk <<= 1) {
                ps += __shfl_xor(ps, mk);
                pd += __shfl_xor(pd, mk);
            }
            if (cc == 0) {
                int row = wm + i * 16 + (lane >> 4) * 4 + r;
                atomicAdd(&sS[row], ps);
                atomicAdd(&sD[row], pd);
            }
        }
    }
    __syncthreads();
    if (tid < 128) {
        int gr = m0 + tid;
        if (gr < M) {
            ssrc[gr * 4 + head] = sS[tid];
            sdst[gr * 4 + head] = sD[tid];
        }
    }
}

// ---------- CSR build ----------
__global__ void k_degree(const int* __restrict__ ei, int* __restrict__ deg) {
    int e = blockIdx.x * blockDim.x + threadIdx.x;
    if (e >= ET_EDGES) return;
    int d = (e < E_EDGES) ? ei[E_EDGES + e] : (e - E_EDGES);
    atomicAdd(&deg[d], 1);
}

// shuffle-based block scan: coalesced loads, wave shfl_up scan; writes offs+cursor
__global__ __launch_bounds__(1024) void k_scan3(const int* __restrict__ deg,
                                                int* __restrict__ offs,
                                                int* __restrict__ cursor) {
    __shared__ int wsum[16];
    __shared__ int carry;
    int t = threadIdx.x;
    int lane = t & 63, wv = t >> 6;
    if (t == 0) carry = 0;
    __syncthreads();
    for (int base = 0; base < N_NODES; base += 1024) {
        int i = base + t;
        int v = (i < N_NODES) ? deg[i] : 0;      // coalesced
        int x = v;
#pragma unroll
        for (int off = 1; off < 64; off <<= 1) { // intra-wave inclusive scan
            int y = __shfl_up(x, off);
            if (lane >= off) x += y;
        }
        if (lane == 63) wsum[wv] = x;
        __syncthreads();
        int wpre = 0;
#pragma unroll
        for (int w = 0; w < 16; ++w) wpre += (w < wv) ? wsum[w] : 0;  // LDS broadcast
        int incl = wpre + x;
        if (i < N_NODES) { int o = carry + (incl - v); offs[i] = o; cursor[i] = o; }
        __syncthreads();
        if (t == 1023) carry += incl;            // row total
        __syncthreads();
    }
    if (t == 0) offs[N_NODES] = carry;
}

__global__ void k_scatter(const int* __restrict__ ei, int* __restrict__ cursor,
                          int* __restrict__ csr_src) {
    int e = blockIdx.x * blockDim.x + threadIdx.x;
    if (e >= ET_EDGES) return;
    int sv, d;
    if (e < E_EDGES) { sv = ei[e]; d = ei[E_EDGES + e]; } else { sv = d = e - E_EDGES; }
    int pos = atomicAdd(&cursor[d], 1);
    csr_src[pos] = sv;
}

__global__ void k_gbounds(const int* __restrict__ batch, int* __restrict__ gstart) {
    int i = blockIdx.x * blockDim.x + threadIdx.x;
    if (i >= N_NODES) return;
    int b = batch[i];
    int p = (i == 0) ? -1 : batch[i - 1];
    for (int g = p + 1; g <= b; ++g) gstart[g] = i;
    if (i == N_NODES - 1)
        for (int g = b + 1; g <= G_GRAPHS; ++g) gstart[g] = N_NODES;
}

// ---------- GAT softmax + aggregate: one wave per dst node ----------
// pass 2 uses a single predicated 8-edge batch (deg<=8 common case: all loads
// issued at once, no serial remainder; clamped duplicate loads are L1-hits).
__global__ __launch_bounds__(256) void k_aggregate(const ushort_t* __restrict__ H,
                                                   const float* __restrict__ ssrc,
                                                   const float* __restrict__ sdst,
                                                   const int* __restrict__ offs,
                                                   const int* __restrict__ csr_src,
                                                   const float* __restrict__ bias,
                                                   ushort_t* __restrict__ out) {
    int wave = threadIdx.x >> 6, lane = threadIdx.x & 63;
    int n = blockIdx.x * 4 + wave;
    if (n >= N_NODES) return;
    int beg = offs[n], end = offs[n + 1];
    int hl = lane >> 4, li = lane & 15;       // head group, index within group
    float sdh = sdst[n * 4 + hl];
    // ---- pass 1: online softmax stats for head hl ----
    float m = -1e30f, s = 0.f;
    for (int e = beg + li; e < end; e += 16) {
        float sc = ssrc[csr_src[e] * 4 + hl] + sdh;
        sc = sc > 0.f ? sc : NEG_SLOPE * sc;
        if (sc > m) { s = s * __expf(m - sc) + 1.f; m = sc; }
        else s += __expf(sc - m);
    }
#pragma unroll
    for (int mk = 1; mk < 16; mk <<= 1) {     // xor<16 stays inside head group
        float om = __shfl_xor(m, mk), os = __shfl_xor(s, mk);
        float mn = fmaxf(m, om);
        s = s * __expf(m - mn) + os * __expf(om - mn);
        m = mn;
    }
    float mh = m, inv = 1.f / s;
    // ---- pass 2: predicated 8-edge batches, all loads independent ----
    float acc[8] = { 0.f, 0.f, 0.f, 0.f, 0.f, 0.f, 0.f, 0.f };
    for (int e0 = beg; e0 < end; e0 += 8) {
        int idx[8];
#pragma unroll
        for (int i = 0; i < 8; ++i) {
            int e = e0 + i;
            idx[i] = csr_src[e < end ? e : end - 1];   // clamp: dup loads are cached
        }
        float sc[8];
#pragma unroll
        for (int i = 0; i < 8; ++i) sc[i] = ssrc[idx[i] * 4 + hl];
        uint4 hv[8];
#pragma unroll
        for (int i = 0; i < 8; ++i)
            hv[i] = *(const uint4*)&H[(size_t)idx[i] * DM + lane * 8];
#pragma unroll
        for (int i = 0; i < 8; ++i) {
            float sx = sc[i] + sdh;
            sx = sx > 0.f ? sx : NEG_SLOPE * sx;
            float alpha = (e0 + i < end) ? __expf(sx - mh) * inv : 0.f;
            float f[8]; unpack8(hv[i], f);
#pragma unroll
            for (int j = 0; j < 8; ++j) acc[j] += alpha * f[j];
        }
    }
    const float* bp = bias + lane * 8;
    float4 b0 = *(const float4*)bp;
    float4 b1 = *(const float4*)(bp + 4);
    acc[0] += b0.x; acc[1] += b0.y; acc[2] += b0.z; acc[3] += b0.w;
    acc[4] += b1.x; acc[5] += b1.y; acc[6] += b1.z; acc[7] += b1.w;
    uint4 ov; unsigned* po = (unsigned*)&ov;
#pragma unroll
    for (int j = 0; j < 4; ++j)
        po[j] = (unsigned)f2b(acc[2 * j]) | ((unsigned)f2b(acc[2 * j + 1]) << 16);
    *(uint4*)&out[(size_t)n * DM + lane * 8] = ov;
}

// ---------- BatchNorm stats: contiguous row slabs, bf16 input ----------
#define BN_ROWS 125   // 400 blocks x 125 rows
__global__ __launch_bounds__(256) void k_bnstats(const ushort_t* __restrict__ X,
                                                 float* __restrict__ stat) {
    int t = threadIdx.x;
    int c2 = t * 2;                       // this thread owns features c2, c2+1
    int beg = blockIdx.x * BN_ROWS;
    int end = beg + BN_ROWS; if (end > N_NODES) end = N_NODES;
    float s0 = 0.f, s1 = 0.f, q0 = 0.f, q1 = 0.f;
    for (int n = beg; n < end; ++n) {     // 256 threads x uint = one full 1KB row
        unsigned v = *(const unsigned*)&X[(size_t)n * DM + c2];
        float x0 = b2f(v & 0xffffu), x1 = b2f(v >> 16);
        s0 += x0; s1 += x1;
        q0 += x0 * x0; q1 += x1 * x1;
    }
    atomicAdd(&stat[c2], s0);
    atomicAdd(&stat[c2 + 1], s1);
    atomicAdd(&stat[512 + c2], q0);
    atomicAdd(&stat[512 + c2 + 1], q1);
}

// ---------- graph pooling, fused bnfin + BN+ReLU: one wave per graph ----------
__global__ __launch_bounds__(64) void k_pool(const ushort_t* __restrict__ X,
                                             const int* __restrict__ gstart,
                                             const float* __restrict__ stat,
                                             const float* __restrict__ gam,
                                             const float* __restrict__ bet,
                                             float* __restrict__ pool) {
    int g = blockIdx.x, t = threadIdx.x;   // 64 threads, 8 feats each
    int beg = gstart[g], end = gstart[g + 1];
    float sc[8], sh[8];
#pragma unroll
    for (int j = 0; j < 8; ++j) {
        int f = t * 8 + j;
        float mu = stat[f] * (1.f / (float)N_NODES);
        float var = fmaxf(stat[512 + f] * (1.f / (float)N_NODES) - mu * mu, 0.f);
        float rs = rsqrtf(var + BN_EPS);
        sc[j] = gam[f] * rs;
        sh[j] = bet[f] - mu * sc[j];
    }
    float sum[8] = { 0 }, mx[8];
#pragma unroll
    for (int j = 0; j < 8; ++j) mx[j] = -1e30f;
    for (int nn = beg; nn < end; ++nn) {
        uint4 xv = *(const uint4*)&X[(size_t)nn * DM + t * 8];
        float f[8]; unpack8(xv, f);
#pragma unroll
        for (int j = 0; j < 8; ++j) {
            f[j] = fmaxf(f[j] * sc[j] + sh[j], 0.f);
            sum[j] += f[j]; mx[j] = fmaxf(mx[j], f[j]);
        }
    }
    float cnt = (float)(end - beg);
    float inv = cnt > 0.f ? 1.f / cnt : 0.f;
#pragma unroll
    for (int j = 0; j < 8; ++j) {
        pool[(size_t)g * 1024 + t * 8 + j] = sum[j] * inv;
        pool[(size_t)g * 1024 + 512 + t * 8 + j] = cnt > 0.f ? mx[j] : 0.f;
    }
}

// ---------- MLP head: one block per graph, 4-way ILP accumulators ----------
__global__ __launch_bounds__(128) void k_mlp(const float* __restrict__ pool,
                                             const float* __restrict__ c1w,
                                             const float* __restrict__ c1b,
                                             const float* __restrict__ c2w,
                                             const float* __restrict__ c2b,
                                             const float* __restrict__ c3w,
                                             const float* __restrict__ c3b,
                                             float* __restrict__ out) {
    __shared__ float row[1024];
    __shared__ float h1[128];
    __shared__ float h2[64];
    int g = blockIdx.x, t = threadIdx.x;
    for (int i = t; i < 1024; i += 128) row[i] = pool[(size_t)g * 1024 + i];
    __syncthreads();
    // 4 independent accumulators: breaks the serial FMA chain, 4 loads in flight
    float p0 = 0.f, p1 = 0.f, p2 = 0.f, p3 = 0.f;
#pragma unroll 2
    for (int k = 0; k < 1024; k += 4) {
        p0 += row[k] * c1w[k * 128 + t];
        p1 += row[k + 1] * c1w[(k + 1) * 128 + t];
        p2 += row[k + 2] * c1w[(k + 2) * 128 + t];
        p3 += row[k + 3] * c1w[(k + 3) * 128 + t];
    }
    h1[t] = fmaxf(c1b[t] + ((p0 + p1) + (p2 + p3)), 0.f);
    __syncthreads();
    if (t < 64) {
        float q0 = 0.f, q1 = 0.f;
#pragma unroll 4
        for (int k = 0; k < 128; k += 2) {
            q0 += h1[k] * c2w[k * 64 + t];
            q1 += h1[k + 1] * c2w[(k + 1) * 64 + t];
        }
        h2[t] = fmaxf(c2b[t] + q0 + q1, 0.f);
    }
    __syncthreads();
    if (t < 64) {
        float p = h2[t] * c3w[t];
#pragma unroll
        for (int off = 32; off > 0; off >>= 1) p += __shfl_down(p, off);
        if (t == 0) {
            float z = p + c3b[0];
            out[g] = 1.f / (1.f + __expf(-z));      // float32 output
        }
    }
}

extern "C" void kernel_launch(void* const* d_in, const int* in_sizes, int n_in,
                              void* d_out, int out_size, void* d_ws, size_t ws_size,
                              hipStream_t stream) {
    const float* x = (const float*)d_in[0];
    const int* ei = (const int*)d_in[1];
    const int* batch = (const int*)d_in[2];
    const float* c1w = (const float*)d_in[21];
    const float* c1b = (const float*)d_in[22];
    const float* c2w = (const float*)d_in[23];
    const float* c2b = (const float*)d_in[24];
    const float* c3w = (const float*)d_in[25];
    const float* c3b = (const float*)d_in[26];

    char* p = (char*)d_ws;
    auto carve = [&](size_t bytes) -> char* {
        char* r = p; p += (bytes + 255) & ~(size_t)255; return r;
    };
    ushort_t* A      = (ushort_t*)carve((size_t)N_NODES * DM * 2);   // activations (pre-BN), bf16
    ushort_t* Hb     = (ushort_t*)carve((size_t)N_NODES * DM * 2);   // h = f(x)@W, bf16
    ushort_t* Xb     = (ushort_t*)carve((size_t)N_NODES * F_IN * 2); // x in bf16
    ushort_t* Wh0    = (ushort_t*)carve((size_t)F_IN * DM * 2);      // W0^T (bf16)
    ushort_t* Wh1    = (ushort_t*)carve((size_t)DM * DM * 2);        // W1^T (bf16)
    ushort_t* Wh2    = (ushort_t*)carve((size_t)DM * DM * 2);        // W2^T (bf16)
    float*    ssrc   = (float*)carve((size_t)N_NODES * 4 * 4);
    float*    sdst   = (float*)carve((size_t)N_NODES * 4 * 4);
    int*      deg    = (int*)carve((size_t)N_NODES * 4);
    int*      offs   = (int*)carve((size_t)(N_NODES + 1) * 4);
    int*      cursor = (int*)carve((size_t)N_NODES * 4);
    int*      csrsrc = (int*)carve((size_t)ET_EDGES * 4);
    float*    bnstat = (float*)carve(3 * 1024 * 4);                  // 3 layers' stats
    int*      gstart = (int*)carve((size_t)(G_GRAPHS + 1) * 4);
    float*    pool   = (float*)carve((size_t)G_GRAPHS * 1024 * 4);

    // --- CSR by dst (self-loops appended) + graph bounds + all dtype prep ---
    hipMemsetAsync(deg, 0, (size_t)N_NODES * 4, stream);
    hipMemsetAsync(bnstat, 0, 3 * 1024 * 4, stream);
    k_degree<<<(ET_EDGES + 255) / 256, 256, 0, stream>>>(ei, deg);
    k_scan3<<<1, 1024, 0, stream>>>(deg, offs, cursor);
    k_scatter<<<(ET_EDGES + 255) / 256, 256, 0, stream>>>(ei, cursor, csrsrc);
    k_gbounds<<<(N_NODES + 255) / 256, 256, 0, stream>>>(batch, gstart);
    {
        int total = XN + W0N + 2 * W1N;
        k_prep<<<(total + 255) / 256, 256, 0, stream>>>(
            x, (const float*)d_in[3], (const float*)d_in[9], (const float*)d_in[15],
            Xb, Wh0, Wh1, Wh2);
    }

    const ushort_t* xin = Xb;
    const ushort_t* Whs[3] = { Wh0, Wh1, Wh2 };
    const float* pstat = nullptr;   // BN raw stats consumed by next mgemm (fused bnfin)
    const float* pgam = nullptr;
    const float* pbet = nullptr;
    for (int l = 0; l < 3; ++l) {
        int K = (l == 0) ? F_IN : DM;
        const float* as_ = (const float*)d_in[4 + 6 * l];
        const float* ad_ = (const float*)d_in[5 + 6 * l];
        const float* bia = (const float*)d_in[6 + 6 * l];
        const float* gam = (const float*)d_in[7 + 6 * l];
        const float* bet = (const float*)d_in[8 + 6 * l];

        k_mgemm<<<4 * YBLK, 256, 0, stream>>>(
            xin, Whs[l], pstat, pgam, pbet, as_, ad_, Hb, ssrc, sdst, N_NODES, K);
        k_aggregate<<<(N_NODES + 3) / 4, 256, 0, stream>>>(Hb, ssrc, sdst, offs, csrsrc, bia, A);
        k_bnstats<<<(N_NODES + BN_ROWS - 1) / BN_ROWS, 256, 0, stream>>>(A, bnstat + l * 1024);
        xin = A; pstat = bnstat + l * 1024; pgam = gam; pbet = bet;
    }
    k_pool<<<G_GRAPHS, 64, 0, stream>>>(A, gstart, bnstat + 2 * 1024, pgam, pbet, pool);
    k_mlp<<<G_GRAPHS, 128, 0, stream>>>(pool, c1w, c1b, c2w, c2b, c3w, c3b,
                                        (float*)d_out);
}

// Round 23
// 695.427 us; speedup vs baseline: 1.0267x; 1.0267x over previous
//
#include <hip/hip_runtime.h>

#define N_NODES 50000
#define E_EDGES 200000
#define ET_EDGES (E_EDGES + N_NODES)
#define G_GRAPHS 2000
#define F_IN 64
#define HID 128
#define HEADS 4
#define DM 512
#define BN_EPS 1e-5f
#define NEG_SLOPE 0.2f
#define YBLK 391            // (N_NODES+127)/128
#define NCHUNK (YBLK / 8)   // 48 full 8-row chunks

typedef unsigned short ushort_t;
typedef float floatx4 __attribute__((ext_vector_type(4)));
typedef short short8 __attribute__((ext_vector_type(8)));

__device__ __forceinline__ float b2f(unsigned int u) {
    union { unsigned int i; float f; } v; v.i = u << 16; return v.f;
}
__device__ __forceinline__ ushort_t f2b(float f) {
    union { float f; unsigned int i; } v; v.f = f;
    unsigned int r = v.i + 0x7FFFu + ((v.i >> 16) & 1u);   // RNE
    return (ushort_t)(r >> 16);
}
__device__ __forceinline__ void unpack8(uint4 v, float* f) {
    f[0] = b2f(v.x & 0xffffu); f[1] = b2f(v.x >> 16);
    f[2] = b2f(v.y & 0xffffu); f[3] = b2f(v.y >> 16);
    f[4] = b2f(v.z & 0xffffu); f[5] = b2f(v.z >> 16);
    f[6] = b2f(v.w & 0xffffu); f[7] = b2f(v.w >> 16);
}

// ---------- combined prep: x->bf16 + 3x W[K,512]->Wt[512,K] bf16 ----------
#define XN (N_NODES * F_IN)
#define W0N (F_IN * DM)
#define W1N (DM * DM)
__global__ __launch_bounds__(256) void k_prep(const float* __restrict__ x,
                                              const float* __restrict__ w0,
                                              const float* __restrict__ w1,
                                              const float* __restrict__ w2,
                                              ushort_t* __restrict__ Xb,
                                              ushort_t* __restrict__ Wh0,
                                              ushort_t* __restrict__ Wh1,
                                              ushort_t* __restrict__ Wh2) {
    int t = blockIdx.x * 256 + threadIdx.x;
    if (t < XN) { Xb[t] = f2b(x[t]); return; }
    t -= XN;
    if (t < W0N) {
        int k = t >> 9, n = t & 511;
        Wh0[(size_t)n * F_IN + k] = f2b(w0[t]);
        return;
    }
    t -= W0N;
    if (t < W1N) {
        int k = t >> 9, n = t & 511;
        Wh1[(size_t)n * DM + k] = f2b(w1[t]);
        return;
    }
    t -= W1N;
    if (t < W1N) {
        int k = t >> 9, n = t & 511;
        Wh2[(size_t)n * DM + k] = f2b(w2[t]);
    }
}

// ---------- MFMA GEMM, software-pipelined: prefetch tile k+1 during MFMA ----------
// C[M,512](bf16) = f(A)[M,K] @ W, f(a)=max(a*scale+shift,0) if stat else a.
// XCD-grouped 1D grid; XOR-swizzled LDS.
__global__ __launch_bounds__(256) void k_mgemm(const ushort_t* __restrict__ A,
                                               const ushort_t* __restrict__ Bh,
                                               const float* __restrict__ stat,
                                               const float* __restrict__ gam,
                                               const float* __restrict__ bet,
                                               const float* __restrict__ a_s,
                                               const float* __restrict__ a_d,
                                               ushort_t* __restrict__ C,
                                               float* __restrict__ ssrc,
                                               float* __restrict__ sdst,
                                               int M, int K) {
    __shared__ __align__(16) ushort_t Ash[128 * 32];
    __shared__ __align__(16) ushort_t Bsh[128 * 32];
    __shared__ float sS[128], sD[128];
    __shared__ float sBs[512], sBt[512];
    // ---- XCD-grouping block index map ----
    int bid = blockIdx.x;
    int head, yb;
    if (bid < NCHUNK * 32) {
        int chunk = bid >> 5, pos = bid & 31;
        yb = chunk * 8 + (pos & 7);
        head = pos >> 3;
    } else {
        int rem = bid - NCHUNK * 32;
        head = rem & 3;
        yb = NCHUNK * 8 + (rem >> 2);
    }
    int m0 = yb * 128, n0 = head * 128;
    int tid = threadIdx.x;
    int lane = tid & 63, wave = tid >> 6;
    int wm = (wave >> 1) * 64, wn = (wave & 1) * 64;
    int r0 = tid >> 2, kv = tid & 3;
    floatx4 acc[4][4] = {};
    bool has_bn = (stat != nullptr);
    if (has_bn) {                     // fused bnfin: scale/shift from raw stats
        for (int f = tid; f < 512; f += 256) {
            float mu = stat[f] * (1.f / (float)N_NODES);
            float var = fmaxf(stat[512 + f] * (1.f / (float)N_NODES) - mu * mu, 0.f);
            float rs = rsqrtf(var + BN_EPS);
            float sc = gam[f] * rs;
            sBs[f] = sc;
            sBt[f] = bet[f] - mu * sc;
        }
    }
    if (tid < 128) { sS[tid] = 0.f; sD[tid] = 0.f; }
    int rA1 = m0 + r0;      if (rA1 >= M) rA1 = M - 1;
    int rA2 = m0 + r0 + 64; if (rA2 >= M) rA2 = M - 1;
    const ushort_t* pa1 = A + (size_t)rA1 * K + kv * 8;
    const ushort_t* pa2 = A + (size_t)rA2 * K + kv * 8;
    const ushort_t* pbh1 = Bh + (size_t)(n0 + r0) * K + kv * 8;
    const ushort_t* pbh2 = Bh + (size_t)(n0 + r0 + 64) * K + kv * 8;
    int rF = lane & 15, q = lane >> 4;
    int swz = ((q ^ (rF & 3) ^ ((rF >> 2) & 3))) * 8;        // read-side chunk pos
    int wswz = ((kv ^ (r0 & 3) ^ ((r0 >> 2) & 3))) * 8;      // write-side chunk pos
    // prefetch tile 0
    uint4 a1 = *(const uint4*)pa1;
    uint4 a2 = *(const uint4*)pa2;
    uint4 b1 = *(const uint4*)pbh1;
    uint4 b2 = *(const uint4*)pbh2;
    for (int k0 = 0; k0 < K; k0 += 32) {
        if (has_bn) {   // fused BN-apply + ReLU on the prefetched registers
            float v1[8], v2[8];
            unpack8(a1, v1); unpack8(a2, v2);
            const float* sp = sBs + k0 + kv * 8;
            const float* tp = sBt + k0 + kv * 8;
            unsigned* q1 = (unsigned*)&a1;
            unsigned* q2 = (unsigned*)&a2;
#pragma unroll
            for (int j = 0; j < 4; ++j) {
                float s0 = sp[2 * j], t0 = tp[2 * j];
                float s1 = sp[2 * j + 1], t1 = tp[2 * j + 1];
                unsigned lo1 = f2b(fmaxf(v1[2 * j] * s0 + t0, 0.f));
                unsigned hi1 = f2b(fmaxf(v1[2 * j + 1] * s1 + t1, 0.f));
                unsigned lo2 = f2b(fmaxf(v2[2 * j] * s0 + t0, 0.f));
                unsigned hi2 = f2b(fmaxf(v2[2 * j + 1] * s1 + t1, 0.f));
                q1[j] = lo1 | (hi1 << 16);
                q2[j] = lo2 | (hi2 << 16);
            }
        }
        __syncthreads();
        *(uint4*)&Ash[r0 * 32 + wswz] = a1;
        *(uint4*)&Ash[(r0 + 64) * 32 + wswz] = a2;
        *(uint4*)&Bsh[r0 * 32 + wswz] = b1;
        *(uint4*)&Bsh[(r0 + 64) * 32 + wswz] = b2;
        __syncthreads();
        if (k0 + 32 < K) {            // prefetch next tile; overlaps ds_read+MFMA
            a1 = *(const uint4*)(pa1 + k0 + 32);
            a2 = *(const uint4*)(pa2 + k0 + 32);
            b1 = *(const uint4*)(pbh1 + k0 + 32);
            b2 = *(const uint4*)(pbh2 + k0 + 32);
        }
        short8 af[4], bf[4];
#pragma unroll
        for (int i = 0; i < 4; ++i)
            af[i] = *(const short8*)&Ash[(wm + i * 16 + rF) * 32 + swz];
#pragma unroll
        for (int j = 0; j < 4; ++j)
            bf[j] = *(const short8*)&Bsh[(wn + j * 16 + rF) * 32 + swz];
#pragma unroll
        for (int i = 0; i < 4; ++i)
#pragma unroll
            for (int j = 0; j < 4; ++j)
                acc[i][j] = __builtin_amdgcn_mfma_f32_16x16x32_bf16(af[i], bf[j], acc[i][j], 0, 0, 0);
    }
    // C/D layout: col=lane&15, row=(lane>>4)*4+reg   [m89-verified]
    int cr = (lane >> 4) * 4, cc = lane & 15;
#pragma unroll
    for (int i = 0; i < 4; ++i) {
#pragma unroll
        for (int r = 0; r < 4; ++r) {
            int gr = m0 + wm + i * 16 + cr + r;
            if (gr < M) {
#pragma unroll
                for (int j = 0; j < 4; ++j)
                    C[(size_t)gr * DM + n0 + wn + j * 16 + cc] = f2b(acc[i][j][r]);
            }
        }
    }
    // ---- fused attention scores (f32 acc, pre-rounding): 128 cols == one head ----
    float asl_[4], adl_[4];
#pragma unroll
    for (int j = 0; j < 4; ++j) {
        int c = wn + j * 16 + cc;
        asl_[j] = a_s[head * HID + c];
        adl_[j] = a_d[head * HID + c];
    }
#pragma unroll
    for (int i = 0; i < 4; ++i) {
#pragma unroll
        for (int r = 0; r < 4; ++r) {
            float ps = 0.f, pd = 0.f;
#pragma unroll
            for (int j = 0; j < 4; ++j) {
                ps += acc[i][j][r] * asl_[j];
                pd += acc[i][j][r] * adl_[j];
            }
#pragma unroll
            for (int mk = 1; mk < 16; mk <<= 1) {
                ps += __shfl_xor(ps, mk);
                pd += __shfl_xor(pd, mk);
            }
            if (cc == 0) {
                int row = wm + i * 16 + (lane >> 4) * 4 + r;
                atomicAdd(&sS[row], ps);
                atomicAdd(&sD[row], pd);
            }
        }
    }
    __syncthreads();
    if (tid < 128) {
        int gr = m0 + tid;
        if (gr < M) {
            ssrc[gr * 4 + head] = sS[tid];
            sdst[gr * 4 + head] = sD[tid];
        }
    }
}

// ---------- CSR build ----------
__global__ void k_degree(const int* __restrict__ ei, int* __restrict__ deg) {
    int e = blockIdx.x * blockDim.x + threadIdx.x;
    if (e >= ET_EDGES) return;
    int d = (e < E_EDGES) ? ei[E_EDGES + e] : (e - E_EDGES);
    atomicAdd(&deg[d], 1);
}

// shuffle-based block scan: coalesced loads, wave shfl_up scan; writes offs+cursor
__global__ __launch_bounds__(1024) void k_scan3(const int* __restrict__ deg,
                                                int* __restrict__ offs,
                                                int* __restrict__ cursor) {
    __shared__ int wsum[16];
    __shared__ int carry;
    int t = threadIdx.x;
    int lane = t & 63, wv = t >> 6;
    if (t == 0) carry = 0;
    __syncthreads();
    for (int base = 0; base < N_NODES; base += 1024) {
        int i = base + t;
        int v = (i < N_NODES) ? deg[i] : 0;      // coalesced
        int x = v;
#pragma unroll
        for (int off = 1; off < 64; off <<= 1) { // intra-wave inclusive scan
            int y = __shfl_up(x, off);
            if (lane >= off) x += y;
        }
        if (lane == 63) wsum[wv] = x;
        __syncthreads();
        int wpre = 0;
#pragma unroll
        for (int w = 0; w < 16; ++w) wpre += (w < wv) ? wsum[w] : 0;  // LDS broadcast
        int incl = wpre + x;
        if (i < N_NODES) { int o = carry + (incl - v); offs[i] = o; cursor[i] = o; }
        __syncthreads();
        if (t == 1023) carry += incl;            // row total
        __syncthreads();
    }
    if (t == 0) offs[N_NODES] = carry;
}

__global__ void k_scatter(const int* __restrict__ ei, int* __restrict__ cursor,
                          int* __restrict__ csr_src) {
    int e = blockIdx.x * blockDim.x + threadIdx.x;
    if (e >= ET_EDGES) return;
    int sv, d;
    if (e < E_EDGES) { sv = ei[e]; d = ei[E_EDGES + e]; } else { sv = d = e - E_EDGES; }
    int pos = atomicAdd(&cursor[d], 1);
    csr_src[pos] = sv;
}

__global__ void k_gbounds(const int* __restrict__ batch, int* __restrict__ gstart) {
    int i = blockIdx.x * blockDim.x + threadIdx.x;
    if (i >= N_NODES) return;
    int b = batch[i];
    int p = (i == 0) ? -1 : batch[i - 1];
    for (int g = p + 1; g <= b; ++g) gstart[g] = i;
    if (i == N_NODES - 1)
        for (int g = b + 1; g <= G_GRAPHS; ++g) gstart[g] = N_NODES;
}

// ---------- GAT softmax + aggregate: one wave per dst node, 4-edge pipelined ----------
__global__ __launch_bounds__(256) void k_aggregate(const ushort_t* __restrict__ H,
                                                   const float* __restrict__ ssrc,
                                                   const float* __restrict__ sdst,
                                                   const int* __restrict__ offs,
                                                   const int* __restrict__ csr_src,
                                                   const float* __restrict__ bias,
                                                   ushort_t* __restrict__ out) {
    int wave = threadIdx.x >> 6, lane = threadIdx.x & 63;
    int n = blockIdx.x * 4 + wave;
    if (n >= N_NODES) return;
    int beg = offs[n], end = offs[n + 1];
    int hl = lane >> 4, li = lane & 15;       // head group, index within group
    float sdh = sdst[n * 4 + hl];
    // ---- pass 1: online softmax stats for head hl ----
    float m = -1e30f, s = 0.f;
    for (int e = beg + li; e < end; e += 16) {
        float sc = ssrc[csr_src[e] * 4 + hl] + sdh;
        sc = sc > 0.f ? sc : NEG_SLOPE * sc;
        if (sc > m) { s = s * __expf(m - sc) + 1.f; m = sc; }
        else s += __expf(sc - m);
    }
#pragma unroll
    for (int mk = 1; mk < 16; mk <<= 1) {     // xor<16 stays inside head group
        float om = __shfl_xor(m, mk), os = __shfl_xor(s, mk);
        float mn = fmaxf(m, om);
        s = s * __expf(m - mn) + os * __expf(om - mn);
        m = mn;
    }
    float mh = m, inv = 1.f / s;
    // ---- pass 2: 4-edge pipelined weighted gather (bf16 rows, 16B/lane) ----
    float acc[8] = { 0.f, 0.f, 0.f, 0.f, 0.f, 0.f, 0.f, 0.f };
    int e = beg;
    for (; e + 4 <= end; e += 4) {
        int sv0 = csr_src[e], sv1 = csr_src[e + 1];
        int sv2 = csr_src[e + 2], sv3 = csr_src[e + 3];
        float s0 = ssrc[sv0 * 4 + hl], s1 = ssrc[sv1 * 4 + hl];
        float s2 = ssrc[sv2 * 4 + hl], s3 = ssrc[sv3 * 4 + hl];
        uint4 h0 = *(const uint4*)&H[(size_t)sv0 * DM + lane * 8];
        uint4 h1 = *(const uint4*)&H[(size_t)sv1 * DM + lane * 8];
        uint4 h2 = *(const uint4*)&H[(size_t)sv2 * DM + lane * 8];
        uint4 h3 = *(const uint4*)&H[(size_t)sv3 * DM + lane * 8];
        s0 += sdh; s0 = s0 > 0.f ? s0 : NEG_SLOPE * s0;
        s1 += sdh; s1 = s1 > 0.f ? s1 : NEG_SLOPE * s1;
        s2 += sdh; s2 = s2 > 0.f ? s2 : NEG_SLOPE * s2;
        s3 += sdh; s3 = s3 > 0.f ? s3 : NEG_SLOPE * s3;
        float a0 = __expf(s0 - mh) * inv, a1 = __expf(s1 - mh) * inv;
        float a2 = __expf(s2 - mh) * inv, a3 = __expf(s3 - mh) * inv;
        float f0[8], f1[8], f2[8], f3[8];
        unpack8(h0, f0); unpack8(h1, f1); unpack8(h2, f2); unpack8(h3, f3);
#pragma unroll
        for (int j = 0; j < 8; ++j)
            acc[j] += a0 * f0[j] + a1 * f1[j] + a2 * f2[j] + a3 * f3[j];
    }
    for (; e < end; ++e) {
        int sv = csr_src[e];
        float sc = ssrc[sv * 4 + hl] + sdh;
        sc = sc > 0.f ? sc : NEG_SLOPE * sc;
        float alpha = __expf(sc - mh) * inv;
        uint4 hv = *(const uint4*)&H[(size_t)sv * DM + lane * 8];
        float f[8]; unpack8(hv, f);
#pragma unroll
        for (int j = 0; j < 8; ++j) acc[j] += alpha * f[j];
    }
    const float* bp = bias + lane * 8;
    float4 b0 = *(const float4*)bp;
    float4 b1 = *(const float4*)(bp + 4);
    acc[0] += b0.x; acc[1] += b0.y; acc[2] += b0.z; acc[3] += b0.w;
    acc[4] += b1.x; acc[5] += b1.y; acc[6] += b1.z; acc[7] += b1.w;
    uint4 ov; unsigned* po = (unsigned*)&ov;
#pragma unroll
    for (int j = 0; j < 4; ++j)
        po[j] = (unsigned)f2b(acc[2 * j]) | ((unsigned)f2b(acc[2 * j + 1]) << 16);
    *(uint4*)&out[(size_t)n * DM + lane * 8] = ov;
}

// ---------- BatchNorm stats: contiguous row slabs, bf16 input ----------
#define BN_ROWS 125   // 400 blocks x 125 rows
__global__ __launch_bounds__(256) void k_bnstats(const ushort_t* __restrict__ X,
                                                 float* __restrict__ stat) {
    int t = threadIdx.x;
    int c2 = t * 2;                       // this thread owns features c2, c2+1
    int beg = blockIdx.x * BN_ROWS;
    int end = beg + BN_ROWS; if (end > N_NODES) end = N_NODES;
    float s0 = 0.f, s1 = 0.f, q0 = 0.f, q1 = 0.f;
    for (int n = beg; n < end; ++n) {     // 256 threads x uint = one full 1KB row
        unsigned v = *(const unsigned*)&X[(size_t)n * DM + c2];
        float x0 = b2f(v & 0xffffu), x1 = b2f(v >> 16);
        s0 += x0; s1 += x1;
        q0 += x0 * x0; q1 += x1 * x1;
    }
    atomicAdd(&stat[c2], s0);
    atomicAdd(&stat[c2 + 1], s1);
    atomicAdd(&stat[512 + c2], q0);
    atomicAdd(&stat[512 + c2 + 1], q1);
}

// ---------- graph pooling, fused bnfin + BN+ReLU: one wave per graph ----------
__global__ __launch_bounds__(64) void k_pool(const ushort_t* __restrict__ X,
                                             const int* __restrict__ gstart,
                                             const float* __restrict__ stat,
                                             const float* __restrict__ gam,
                                             const float* __restrict__ bet,
                                             float* __restrict__ pool) {
    int g = blockIdx.x, t = threadIdx.x;   // 64 threads, 8 feats each
    int beg = gstart[g], end = gstart[g + 1];
    float sc[8], sh[8];
#pragma unroll
    for (int j = 0; j < 8; ++j) {
        int f = t * 8 + j;
        float mu = stat[f] * (1.f / (float)N_NODES);
        float var = fmaxf(stat[512 + f] * (1.f / (float)N_NODES) - mu * mu, 0.f);
        float rs = rsqrtf(var + BN_EPS);
        sc[j] = gam[f] * rs;
        sh[j] = bet[f] - mu * sc[j];
    }
    float sum[8] = { 0 }, mx[8];
#pragma unroll
    for (int j = 0; j < 8; ++j) mx[j] = -1e30f;
    for (int nn = beg; nn < end; ++nn) {
        uint4 xv = *(const uint4*)&X[(size_t)nn * DM + t * 8];
        float f[8]; unpack8(xv, f);
#pragma unroll
        for (int j = 0; j < 8; ++j) {
            f[j] = fmaxf(f[j] * sc[j] + sh[j], 0.f);
            sum[j] += f[j]; mx[j] = fmaxf(mx[j], f[j]);
        }
    }
    float cnt = (float)(end - beg);
    float inv = cnt > 0.f ? 1.f / cnt : 0.f;
#pragma unroll
    for (int j = 0; j < 8; ++j) {
        pool[(size_t)g * 1024 + t * 8 + j] = sum[j] * inv;
        pool[(size_t)g * 1024 + 512 + t * 8 + j] = cnt > 0.f ? mx[j] : 0.f;
    }
}

// ---------- MLP head: one block per graph; f32 throughout ----------
__global__ __launch_bounds__(128) void k_mlp(const float* __restrict__ pool,
                                             const float* __restrict__ c1w,
                                             const float* __restrict__ c1b,
                                             const float* __restrict__ c2w,
                                             const float* __restrict__ c2b,
                                             const float* __restrict__ c3w,
                                             const float* __restrict__ c3b,
                                             float* __restrict__ out) {
    __shared__ float row[1024];
    __shared__ float h1[128];
    __shared__ float h2[64];
    int g = blockIdx.x, t = threadIdx.x;
    for (int i = t; i < 1024; i += 128) row[i] = pool[(size_t)g * 1024 + i];
    __syncthreads();
    float a1 = c1b[t];
#pragma unroll 8
    for (int k = 0; k < 1024; ++k) a1 += row[k] * c1w[k * 128 + t];
    h1[t] = fmaxf(a1, 0.f);
    __syncthreads();
    if (t < 64) {
        float a2 = c2b[t];
#pragma unroll 8
        for (int k = 0; k < 128; ++k) a2 += h1[k] * c2w[k * 64 + t];
        h2[t] = fmaxf(a2, 0.f);
    }
    __syncthreads();
    if (t < 64) {
        float p = h2[t] * c3w[t];
#pragma unroll
        for (int off = 32; off > 0; off >>= 1) p += __shfl_down(p, off);
        if (t == 0) {
            float z = p + c3b[0];
            out[g] = 1.f / (1.f + __expf(-z));      // float32 output
        }
    }
}

extern "C" void kernel_launch(void* const* d_in, const int* in_sizes, int n_in,
                              void* d_out, int out_size, void* d_ws, size_t ws_size,
                              hipStream_t stream) {
    const float* x = (const float*)d_in[0];
    const int* ei = (const int*)d_in[1];
    const int* batch = (const int*)d_in[2];
    const float* c1w = (const float*)d_in[21];
    const float* c1b = (const float*)d_in[22];
    const float* c2w = (const float*)d_in[23];
    const float* c2b = (const float*)d_in[24];
    const float* c3w = (const float*)d_in[25];
    const float* c3b = (const float*)d_in[26];

    char* p = (char*)d_ws;
    auto carve = [&](size_t bytes) -> char* {
        char* r = p; p += (bytes + 255) & ~(size_t)255; return r;
    };
    ushort_t* A      = (ushort_t*)carve((size_t)N_NODES * DM * 2);   // activations (pre-BN), bf16
    ushort_t* Hb     = (ushort_t*)carve((size_t)N_NODES * DM * 2);   // h = f(x)@W, bf16
    ushort_t* Xb     = (ushort_t*)carve((size_t)N_NODES * F_IN * 2); // x in bf16
    ushort_t* Wh0    = (ushort_t*)carve((size_t)F_IN * DM * 2);      // W0^T (bf16)
    ushort_t* Wh1    = (ushort_t*)carve((size_t)DM * DM * 2);        // W1^T (bf16)
    ushort_t* Wh2    = (ushort_t*)carve((size_t)DM * DM * 2);        // W2^T (bf16)
    float*    ssrc   = (float*)carve((size_t)N_NODES * 4 * 4);
    float*    sdst   = (float*)carve((size_t)N_NODES * 4 * 4);
    int*      deg    = (int*)carve((size_t)N_NODES * 4);
    int*      offs   = (int*)carve((size_t)(N_NODES + 1) * 4);
    int*      cursor = (int*)carve((size_t)N_NODES * 4);
    int*      csrsrc = (int*)carve((size_t)ET_EDGES * 4);
    float*    bnstat = (float*)carve(3 * 1024 * 4);                  // 3 layers' stats
    int*      gstart = (int*)carve((size_t)(G_GRAPHS + 1) * 4);
    float*    pool   = (float*)carve((size_t)G_GRAPHS * 1024 * 4);

    // --- CSR by dst (self-loops appended) + graph bounds + all dtype prep ---
    hipMemsetAsync(deg, 0, (size_t)N_NODES * 4, stream);
    hipMemsetAsync(bnstat, 0, 3 * 1024 * 4, stream);
    k_degree<<<(ET_EDGES + 255) / 256, 256, 0, stream>>>(ei, deg);
    k_scan3<<<1, 1024, 0, stream>>>(deg, offs, cursor);
    k_scatter<<<(ET_EDGES + 255) / 256, 256, 0, stream>>>(ei, cursor, csrsrc);
    k_gbounds<<<(N_NODES + 255) / 256, 256, 0, stream>>>(batch, gstart);
    {
        int total = XN + W0N + 2 * W1N;
        k_prep<<<(total + 255) / 256, 256, 0, stream>>>(
            x, (const float*)d_in[3], (const float*)d_in[9], (const float*)d_in[15],
            Xb, Wh0, Wh1, Wh2);
    }

    const ushort_t* xin = Xb;
    const ushort_t* Whs[3] = { Wh0, Wh1, Wh2 };
    const float* pstat = nullptr;   // BN raw stats consumed by next mgemm (fused bnfin)
    const float* pgam = nullptr;
    const float* pbet = nullptr;
    for (int l = 0; l < 3; ++l) {
        int K = (l == 0) ? F_IN : DM;
        const float* as_ = (const float*)d_in[4 + 6 * l];
        const float* ad_ = (const float*)d_in[5 + 6 * l];
        const float* bia = (const float*)d_in[6 + 6 * l];
        const float* gam = (const float*)d_in[7 + 6 * l];
        const float* bet = (const float*)d_in[8 + 6 * l];

        k_mgemm<<<4 * YBLK, 256, 0, stream>>>(
            xin, Whs[l], pstat, pgam, pbet, as_, ad_, Hb, ssrc, sdst, N_NODES, K);
        k_aggregate<<<(N_NODES + 3) / 4, 256, 0, stream>>>(Hb, ssrc, sdst, offs, csrsrc, bia, A);
        k_bnstats<<<(N_NODES + BN_ROWS - 1) / BN_ROWS, 256, 0, stream>>>(A, bnstat + l * 1024);
        xin = A; pstat = bnstat + l * 1024; pgam = gam; pbet = bet;
    }
    k_pool<<<G_GRAPHS, 64, 0, stream>>>(A, gstart, bnstat + 2 * 1024, pgam, pbet, pool);
    k_mlp<<<G_GRAPHS, 128, 0, stream>>>(pool, c1w, c1b, c2w, c2b, c3w, c3b,
                                        (float*)d_out);
}